// Round 1
// baseline (308.924 us; speedup 1.0000x reference)
//
#include <hip/hip_runtime.h>
#include <hip/hip_bf16.h>

// GCN 2-layer + classifier, fp32.
// x:[n,64] edge_index:[2,E] int32, W1:[64,64] b1:[64] W2:[64,64] b2:[64] Wc:[64,16] bc:[16]
// out:[n,16] fp32.
// Plan per launch:
//   1. deg histogram over dst (atomicAdd int)
//   2. inv[i] = rsqrt(deg[i]+1)   (+1 = self-loop)
//   3. exclusive scan deg -> row_ptr (CSR by dst)
//   4. fill col[] (src) + wgt[] (inv[src]*inv[dst]) via per-node atomic cursor
//   5. P = x@W1 ; A = relu(agg(P)+b1) ; P = A@W2 ; A = relu(agg(P)+b2) ; out = A@Wc+bc
// agg: one wave per node, one lane per feature -> coalesced 256B row gathers, no atomics.

#define FDIM 64
#define NCLS 16

__global__ __launch_bounds__(256) void k_deg(const int* __restrict__ dst, int E, int* __restrict__ deg) {
    int e = blockIdx.x * 256 + threadIdx.x;
    if (e < E) atomicAdd(&deg[dst[e]], 1);
}

__global__ __launch_bounds__(256) void k_inv(const int* __restrict__ deg, float* __restrict__ inv, int n) {
    int i = blockIdx.x * 256 + threadIdx.x;
    if (i < n) inv[i] = rsqrtf((float)(deg[i] + 1));
}

__global__ __launch_bounds__(256) void k_block_sums(const int* __restrict__ deg, int n, int* __restrict__ bsum) {
    __shared__ int s[256];
    int t = threadIdx.x;
    int i = blockIdx.x * 256 + t;
    s[t] = (i < n) ? deg[i] : 0;
    __syncthreads();
    for (int off = 128; off > 0; off >>= 1) {
        if (t < off) s[t] += s[t + off];
        __syncthreads();
    }
    if (t == 0) bsum[blockIdx.x] = s[0];
}

// single block, nb <= 256: exclusive scan of bsum, total -> *total
__global__ __launch_bounds__(256) void k_scan_bsums(int* __restrict__ bsum, int nb, int* __restrict__ total) {
    __shared__ int s[256];
    int t = threadIdx.x;
    int v = (t < nb) ? bsum[t] : 0;
    s[t] = v;
    __syncthreads();
    for (int off = 1; off < 256; off <<= 1) {
        int add = (t >= off) ? s[t - off] : 0;
        __syncthreads();
        s[t] += add;
        __syncthreads();
    }
    if (t < nb) bsum[t] = s[t] - v;   // exclusive
    if (t == 255) *total = s[255];
}

__global__ __launch_bounds__(256) void k_scan_chunks(const int* __restrict__ deg, int n,
                                                     const int* __restrict__ bsum, int* __restrict__ row_ptr) {
    __shared__ int s[256];
    int t = threadIdx.x;
    int i = blockIdx.x * 256 + t;
    int v = (i < n) ? deg[i] : 0;
    s[t] = v;
    __syncthreads();
    for (int off = 1; off < 256; off <<= 1) {
        int add = (t >= off) ? s[t - off] : 0;
        __syncthreads();
        s[t] += add;
        __syncthreads();
    }
    if (i < n) row_ptr[i] = bsum[blockIdx.x] + s[t] - v;  // exclusive
}

__global__ __launch_bounds__(256) void k_fill(const int* __restrict__ src, const int* __restrict__ dst, int E,
                                              const int* __restrict__ row_ptr, int* __restrict__ cnt,
                                              int* __restrict__ col, float* __restrict__ wgt,
                                              const float* __restrict__ inv) {
    int e = blockIdx.x * 256 + threadIdx.x;
    if (e >= E) return;
    int s = src[e], d = dst[e];
    int pos = row_ptr[d] + atomicAdd(&cnt[d], 1);
    col[pos] = s;
    wgt[pos] = inv[s] * inv[d];
}

// Y[n,64] = X[n,64] @ W[64,64]  (no bias). thread = (row, 16-col group)
__global__ __launch_bounds__(256) void k_gemm64(const float* __restrict__ X, const float* __restrict__ W,
                                                float* __restrict__ Y, int n) {
    __shared__ float Ws[FDIM * FDIM];
    int t = threadIdx.x;
    for (int i = t; i < FDIM * FDIM; i += 256) Ws[i] = W[i];
    __syncthreads();
    int idx = blockIdx.x * 256 + t;
    int row = idx >> 2;
    int cg = (idx & 3) * 16;
    if (row >= n) return;
    const float4* xr = (const float4*)(X + row * FDIM);
    float4 xv[16];
#pragma unroll
    for (int i = 0; i < 16; ++i) xv[i] = xr[i];
    float acc[16];
#pragma unroll
    for (int c = 0; c < 16; ++c) acc[c] = 0.f;
#pragma unroll
    for (int i = 0; i < 16; ++i) {
        float xs[4] = {xv[i].x, xv[i].y, xv[i].z, xv[i].w};
#pragma unroll
        for (int j = 0; j < 4; ++j) {
            float xk = xs[j];
            const float* wr = &Ws[(i * 4 + j) * FDIM + cg];
#pragma unroll
            for (int c = 0; c < 16; ++c) acc[c] += xk * wr[c];
        }
    }
    float4* yo = (float4*)(Y + row * FDIM + cg);
#pragma unroll
    for (int q = 0; q < 4; ++q)
        yo[q] = make_float4(acc[q * 4], acc[q * 4 + 1], acc[q * 4 + 2], acc[q * 4 + 3]);
}

// out[node][lane] = sum_{edges->node} wgt*P[src][lane] + inv[node]^2*P[node][lane] + bias[lane]; opt relu
__global__ __launch_bounds__(256) void k_agg(const float* __restrict__ P, const float* __restrict__ inv,
                                             const int* __restrict__ row_ptr, const int* __restrict__ col,
                                             const float* __restrict__ wgt, const float* __restrict__ bias,
                                             float* __restrict__ out, int n, int relu) {
    int wid = __builtin_amdgcn_readfirstlane(threadIdx.x >> 6);
    int lane = threadIdx.x & 63;
    int node = blockIdx.x * 4 + wid;
    if (node >= n) return;
    float iv = inv[node];
    float acc = P[node * FDIM + lane] * iv * iv;
    int s = row_ptr[node], e = row_ptr[node + 1];
    for (int j = s; j < e; ++j) {
        int c = col[j];
        float w = wgt[j];
        acc += w * P[c * FDIM + lane];
    }
    acc += bias[lane];
    if (relu) acc = fmaxf(acc, 0.f);
    out[node * FDIM + lane] = acc;
}

// out[n,16] = X[n,64] @ Wc[64,16] + bc. thread = (row, 4-col group)
__global__ __launch_bounds__(256) void k_cls(const float* __restrict__ X, const float* __restrict__ W,
                                             const float* __restrict__ b, float* __restrict__ Y, int n) {
    __shared__ float Ws[FDIM * NCLS];
    __shared__ float bs[NCLS];
    int t = threadIdx.x;
    for (int i = t; i < FDIM * NCLS; i += 256) Ws[i] = W[i];
    if (t < NCLS) bs[t] = b[t];
    __syncthreads();
    int idx = blockIdx.x * 256 + t;
    int row = idx >> 2;
    int cg = (idx & 3) * 4;
    if (row >= n) return;
    const float4* xr = (const float4*)(X + row * FDIM);
    float a0 = bs[cg], a1 = bs[cg + 1], a2 = bs[cg + 2], a3 = bs[cg + 3];
#pragma unroll
    for (int i = 0; i < 16; ++i) {
        float4 xq = xr[i];
        float xs[4] = {xq.x, xq.y, xq.z, xq.w};
#pragma unroll
        for (int j = 0; j < 4; ++j) {
            float xk = xs[j];
            const float* wr = &Ws[(i * 4 + j) * NCLS + cg];
            a0 += xk * wr[0];
            a1 += xk * wr[1];
            a2 += xk * wr[2];
            a3 += xk * wr[3];
        }
    }
    *(float4*)(Y + row * NCLS + cg) = make_float4(a0, a1, a2, a3);
}

static inline size_t align256(size_t x) { return (x + 255) & ~(size_t)255; }

extern "C" void kernel_launch(void* const* d_in, const int* in_sizes, int n_in,
                              void* d_out, int out_size, void* d_ws, size_t ws_size,
                              hipStream_t stream) {
    const float* x  = (const float*)d_in[0];
    const int*   ei = (const int*)d_in[1];
    const float* W1 = (const float*)d_in[2];
    const float* b1 = (const float*)d_in[3];
    const float* W2 = (const float*)d_in[4];
    const float* b2 = (const float*)d_in[5];
    const float* Wc = (const float*)d_in[6];
    const float* bc = (const float*)d_in[7];
    float* out = (float*)d_out;

    const int n = in_sizes[0] / FDIM;   // 50000
    const int E = in_sizes[1] / 2;      // 800000
    const int* src = ei;
    const int* dst = ei + E;

    // workspace carve-up
    char* w = (char*)d_ws;
    size_t off = 0;
    int* deg = (int*)(w + off);      off = align256(off + (size_t)n * 4);
    int* cnt = (int*)(w + off);      off = align256(off + (size_t)n * 4);
    int* row_ptr = (int*)(w + off);  off = align256(off + (size_t)(n + 1) * 4);
    int* bsum = (int*)(w + off);     off = align256(off + 256 * 4);
    float* inv = (float*)(w + off);  off = align256(off + (size_t)n * 4);
    int* col = (int*)(w + off);      off = align256(off + (size_t)E * 4);
    float* wgt = (float*)(w + off);  off = align256(off + (size_t)E * 4);
    float* P = (float*)(w + off);    off = align256(off + (size_t)n * FDIM * 4);
    float* A = (float*)(w + off);    off = align256(off + (size_t)n * FDIM * 4);
    (void)ws_size;

    const int nbE = (E + 255) / 256;
    const int nbN = (n + 255) / 256;
    const int nbG = (n * 4 + 255) / 256;
    const int nbA = (n + 3) / 4;

    // zero deg + cnt (adjacent is not guaranteed after align; memset separately)
    hipMemsetAsync(deg, 0, (size_t)n * 4, stream);
    hipMemsetAsync(cnt, 0, (size_t)n * 4, stream);

    // 1-2: degree + inv sqrt
    k_deg<<<nbE, 256, 0, stream>>>(dst, E, deg);
    k_inv<<<nbN, 256, 0, stream>>>(deg, inv, n);

    // 3: scan -> row_ptr  (nbN = 196 <= 256 fits one-block scan)
    k_block_sums<<<nbN, 256, 0, stream>>>(deg, n, bsum);
    k_scan_bsums<<<1, 256, 0, stream>>>(bsum, nbN, row_ptr + n);
    k_scan_chunks<<<nbN, 256, 0, stream>>>(deg, n, bsum, row_ptr);

    // 4: fill CSR with precomputed weights
    k_fill<<<nbE, 256, 0, stream>>>(src, dst, E, row_ptr, cnt, col, wgt, inv);

    // 5: layer 1
    k_gemm64<<<nbG, 256, 0, stream>>>(x, W1, P, n);
    k_agg<<<nbA, 256, 0, stream>>>(P, inv, row_ptr, col, wgt, b1, A, n, 1);
    // layer 2
    k_gemm64<<<nbG, 256, 0, stream>>>(A, W2, P, n);
    k_agg<<<nbA, 256, 0, stream>>>(P, inv, row_ptr, col, wgt, b2, A, n, 1);
    // classifier
    k_cls<<<nbG, 256, 0, stream>>>(A, Wc, bc, out, n);
}

// Round 2
// 267.122 us; speedup vs baseline: 1.1565x; 1.1565x over previous
//
#include <hip/hip_runtime.h>
#include <hip/hip_bf16.h>

// GCN 2-layer + classifier, fp32.
// x:[n,64] edge_index:[2,E] int32, W1:[64,64] b1:[64] W2:[64,64] b2:[64] Wc:[64,16] bc:[16]
// out:[n,16] fp32.
// CSR-by-dst built per launch; edge record packed as int2{src, bits(inv[src])} so
// k_fill touches ONE random cache line per edge and k_agg gets weight+col in one
// wave-uniform (scalar) 8B load. inv[dst] factors out of the gather loop.
// k_agg: wave per node, lane per feature, edge loop unrolled x4 for MLP.

#define FDIM 64
#define NCLS 16

__global__ __launch_bounds__(256) void k_deg(const int* __restrict__ dst, int E, int* __restrict__ deg) {
    int e = blockIdx.x * 256 + threadIdx.x;
    if (e < E) atomicAdd(&deg[dst[e]], 1);
}

// inv = rsqrt(deg+1) fused with per-block degree sums (both read deg once)
__global__ __launch_bounds__(256) void k_prep(const int* __restrict__ deg, int n,
                                              float* __restrict__ inv, int* __restrict__ bsum) {
    __shared__ int s[256];
    int t = threadIdx.x;
    int i = blockIdx.x * 256 + t;
    int d = (i < n) ? deg[i] : 0;
    if (i < n) inv[i] = rsqrtf((float)(d + 1));
    s[t] = d;
    __syncthreads();
    for (int off = 128; off > 0; off >>= 1) {
        if (t < off) s[t] += s[t + off];
        __syncthreads();
    }
    if (t == 0) bsum[blockIdx.x] = s[0];
}

// single block, nb <= 256: exclusive scan of bsum, total -> *total
__global__ __launch_bounds__(256) void k_scan_bsums(int* __restrict__ bsum, int nb, int* __restrict__ total) {
    __shared__ int s[256];
    int t = threadIdx.x;
    int v = (t < nb) ? bsum[t] : 0;
    s[t] = v;
    __syncthreads();
    for (int off = 1; off < 256; off <<= 1) {
        int add = (t >= off) ? s[t - off] : 0;
        __syncthreads();
        s[t] += add;
        __syncthreads();
    }
    if (t < nb) bsum[t] = s[t] - v;   // exclusive
    if (t == 255) *total = s[255];
}

__global__ __launch_bounds__(256) void k_scan_chunks(const int* __restrict__ deg, int n,
                                                     const int* __restrict__ bsum, int* __restrict__ row_ptr) {
    __shared__ int s[256];
    int t = threadIdx.x;
    int i = blockIdx.x * 256 + t;
    int v = (i < n) ? deg[i] : 0;
    s[t] = v;
    __syncthreads();
    for (int off = 1; off < 256; off <<= 1) {
        int add = (t >= off) ? s[t - off] : 0;
        __syncthreads();
        s[t] += add;
        __syncthreads();
    }
    if (i < n) row_ptr[i] = bsum[blockIdx.x] + s[t] - v;  // exclusive
}

__global__ __launch_bounds__(256) void k_fill(const int* __restrict__ src, const int* __restrict__ dst, int E,
                                              const int* __restrict__ row_ptr, int* __restrict__ cnt,
                                              int2* __restrict__ cw, const float* __restrict__ inv) {
    int e = blockIdx.x * 256 + threadIdx.x;
    if (e >= E) return;
    int s = src[e], d = dst[e];
    int pos = row_ptr[d] + atomicAdd(&cnt[d], 1);
    cw[pos] = make_int2(s, __float_as_int(inv[s]));   // one 8B store, one random line
}

// Y[n,64] = X[n,64] @ W[64,64]  (no bias). thread = (row, 16-col group)
__global__ __launch_bounds__(256) void k_gemm64(const float* __restrict__ X, const float* __restrict__ W,
                                                float* __restrict__ Y, int n) {
    __shared__ float Ws[FDIM * FDIM];
    int t = threadIdx.x;
    for (int i = t; i < FDIM * FDIM; i += 256) Ws[i] = W[i];
    __syncthreads();
    int idx = blockIdx.x * 256 + t;
    int row = idx >> 2;
    int cg = (idx & 3) * 16;
    if (row >= n) return;
    const float4* xr = (const float4*)(X + row * FDIM);
    float4 xv[16];
#pragma unroll
    for (int i = 0; i < 16; ++i) xv[i] = xr[i];
    float acc[16];
#pragma unroll
    for (int c = 0; c < 16; ++c) acc[c] = 0.f;
#pragma unroll
    for (int i = 0; i < 16; ++i) {
        float xs[4] = {xv[i].x, xv[i].y, xv[i].z, xv[i].w};
#pragma unroll
        for (int j = 0; j < 4; ++j) {
            float xk = xs[j];
            const float* wr = &Ws[(i * 4 + j) * FDIM + cg];
#pragma unroll
            for (int c = 0; c < 16; ++c) acc[c] += xk * wr[c];
        }
    }
    float4* yo = (float4*)(Y + row * FDIM + cg);
#pragma unroll
    for (int q = 0; q < 4; ++q)
        yo[q] = make_float4(acc[q * 4], acc[q * 4 + 1], acc[q * 4 + 2], acc[q * 4 + 3]);
}

// out[node][lane] = inv[d]*( sum_edges inv[s]*P[s][lane] + inv[d]*P[d][lane] ) + bias; opt relu
__global__ __launch_bounds__(256) void k_agg(const float* __restrict__ P, const float* __restrict__ inv,
                                             const int* __restrict__ row_ptr, const int2* __restrict__ cw,
                                             const float* __restrict__ bias,
                                             float* __restrict__ out, int n, int relu) {
    int wid = __builtin_amdgcn_readfirstlane(threadIdx.x >> 6);
    int lane = threadIdx.x & 63;
    int node = blockIdx.x * 4 + wid;
    if (node >= n) return;
    float iv = inv[node];
    float acc = P[node * FDIM + lane] * iv;   // self term (x iv again at end)
    int s = row_ptr[node], e = row_ptr[node + 1];
    int j = s;
    // unroll x4: 4 independent gathers in flight per wave
    for (; j + 4 <= e; j += 4) {
        int2 a0 = cw[j];
        int2 a1 = cw[j + 1];
        int2 a2 = cw[j + 2];
        int2 a3 = cw[j + 3];
        float p0 = P[(size_t)a0.x * FDIM + lane];
        float p1 = P[(size_t)a1.x * FDIM + lane];
        float p2 = P[(size_t)a2.x * FDIM + lane];
        float p3 = P[(size_t)a3.x * FDIM + lane];
        acc = fmaf(__int_as_float(a0.y), p0, acc);
        acc = fmaf(__int_as_float(a1.y), p1, acc);
        acc = fmaf(__int_as_float(a2.y), p2, acc);
        acc = fmaf(__int_as_float(a3.y), p3, acc);
    }
    for (; j < e; ++j) {
        int2 a = cw[j];
        acc = fmaf(__int_as_float(a.y), P[(size_t)a.x * FDIM + lane], acc);
    }
    acc = fmaf(iv, acc, bias[lane]);
    if (relu) acc = fmaxf(acc, 0.f);
    out[node * FDIM + lane] = acc;
}

// out[n,16] = X[n,64] @ Wc[64,16] + bc. thread = (row, 4-col group)
__global__ __launch_bounds__(256) void k_cls(const float* __restrict__ X, const float* __restrict__ W,
                                             const float* __restrict__ b, float* __restrict__ Y, int n) {
    __shared__ float Ws[FDIM * NCLS];
    __shared__ float bs[NCLS];
    int t = threadIdx.x;
    for (int i = t; i < FDIM * NCLS; i += 256) Ws[i] = W[i];
    if (t < NCLS) bs[t] = b[t];
    __syncthreads();
    int idx = blockIdx.x * 256 + t;
    int row = idx >> 2;
    int cg = (idx & 3) * 4;
    if (row >= n) return;
    const float4* xr = (const float4*)(X + row * FDIM);
    float a0 = bs[cg], a1 = bs[cg + 1], a2 = bs[cg + 2], a3 = bs[cg + 3];
#pragma unroll
    for (int i = 0; i < 16; ++i) {
        float4 xq = xr[i];
        float xs[4] = {xq.x, xq.y, xq.z, xq.w};
#pragma unroll
        for (int j = 0; j < 4; ++j) {
            float xk = xs[j];
            const float* wr = &Ws[(i * 4 + j) * NCLS + cg];
            a0 += xk * wr[0];
            a1 += xk * wr[1];
            a2 += xk * wr[2];
            a3 += xk * wr[3];
        }
    }
    *(float4*)(Y + row * NCLS + cg) = make_float4(a0, a1, a2, a3);
}

static inline size_t align256(size_t x) { return (x + 255) & ~(size_t)255; }

extern "C" void kernel_launch(void* const* d_in, const int* in_sizes, int n_in,
                              void* d_out, int out_size, void* d_ws, size_t ws_size,
                              hipStream_t stream) {
    const float* x  = (const float*)d_in[0];
    const int*   ei = (const int*)d_in[1];
    const float* W1 = (const float*)d_in[2];
    const float* b1 = (const float*)d_in[3];
    const float* W2 = (const float*)d_in[4];
    const float* b2 = (const float*)d_in[5];
    const float* Wc = (const float*)d_in[6];
    const float* bc = (const float*)d_in[7];
    float* out = (float*)d_out;

    const int n = in_sizes[0] / FDIM;   // 50000
    const int E = in_sizes[1] / 2;      // 800000
    const int* src = ei;
    const int* dst = ei + E;

    // workspace carve-up
    char* w = (char*)d_ws;
    size_t off = 0;
    int* deg = (int*)(w + off);      off = align256(off + (size_t)n * 4);
    int* cnt = (int*)(w + off);      off = align256(off + (size_t)n * 4);
    int* row_ptr = (int*)(w + off);  off = align256(off + (size_t)(n + 1) * 4);
    int* bsum = (int*)(w + off);     off = align256(off + 256 * 4);
    float* inv = (float*)(w + off);  off = align256(off + (size_t)n * 4);
    int2* cw = (int2*)(w + off);     off = align256(off + (size_t)E * 8);
    float* P = (float*)(w + off);    off = align256(off + (size_t)n * FDIM * 4);
    float* A = (float*)(w + off);    off = align256(off + (size_t)n * FDIM * 4);
    (void)ws_size;

    const int nbE = (E + 255) / 256;
    const int nbN = (n + 255) / 256;
    const int nbG = (n * 4 + 255) / 256;
    const int nbA = (n + 3) / 4;

    hipMemsetAsync(deg, 0, (size_t)n * 4, stream);
    hipMemsetAsync(cnt, 0, (size_t)n * 4, stream);

    // degree + inv + scan -> row_ptr  (nbN = 196 <= 256 fits one-block scan)
    k_deg<<<nbE, 256, 0, stream>>>(dst, E, deg);
    k_prep<<<nbN, 256, 0, stream>>>(deg, n, inv, bsum);
    k_scan_bsums<<<1, 256, 0, stream>>>(bsum, nbN, row_ptr + n);
    k_scan_chunks<<<nbN, 256, 0, stream>>>(deg, n, bsum, row_ptr);

    // fill packed CSR
    k_fill<<<nbE, 256, 0, stream>>>(src, dst, E, row_ptr, cnt, cw, inv);

    // layer 1
    k_gemm64<<<nbG, 256, 0, stream>>>(x, W1, P, n);
    k_agg<<<nbA, 256, 0, stream>>>(P, inv, row_ptr, cw, b1, A, n, 1);
    // layer 2
    k_gemm64<<<nbG, 256, 0, stream>>>(A, W2, P, n);
    k_agg<<<nbA, 256, 0, stream>>>(P, inv, row_ptr, cw, b2, A, n, 1);
    // classifier
    k_cls<<<nbG, 256, 0, stream>>>(A, Wc, bc, out, n);
}